// Round 1
// baseline (374.289 us; speedup 1.0000x reference)
//
#include <hip/hip_runtime.h>

#define TQS 4096
#define TKS 4096
#define DM 2048
#define NH 4
#define DI 64
#define BB 2

typedef __attribute__((ext_vector_type(4))) float f32x4;
typedef __attribute__((ext_vector_type(8))) short bf16x8;

__device__ __forceinline__ short f2bf(float f) {
  union { float f; unsigned u; } v; v.f = f;
  unsigned r = v.u + 0x7fffu + ((v.u >> 16) & 1u);
  return (short)(r >> 16);
}

__device__ __forceinline__ bf16x8 cvt8(const float* p) {
  f32x4 lo = *(const f32x4*)p;
  f32x4 hi = *(const f32x4*)(p + 4);
  bf16x8 r;
  r[0] = f2bf(lo[0]); r[1] = f2bf(lo[1]); r[2] = f2bf(lo[2]); r[3] = f2bf(lo[3]);
  r[4] = f2bf(hi[0]); r[5] = f2bf(hi[1]); r[6] = f2bf(hi[2]); r[7] = f2bf(hi[3]);
  return r;
}

// WT[n][k] = (bf16) W[k][n];  W is [2048][N] row-major f32.
__global__ void transpose_cast_kernel(const float* __restrict__ W,
                                      short* __restrict__ WT, int N) {
  int idx = blockIdx.x * 256 + threadIdx.x;   // idx = n*2048 + k
  int n = idx >> 11;
  int k = idx & 2047;
  WT[idx] = f2bf(W[(size_t)k * N + n]);
}

// O[M][Ncols] (bf16) = cast(X[M][2048] f32) @ W, with W given as WT[n][2048] bf16.
// Block: 256 threads (4 waves); block tile (64*MI) rows x 64 cols; wave tile 16*MI x 64.
template <int MI>
__global__ __launch_bounds__(256) void proj_kernel(const float* __restrict__ X,
                                                   const short* __restrict__ WT,
                                                   short* __restrict__ O, int Ncols) {
  const int tid = threadIdx.x;
  const int wave = tid >> 6, lane = tid & 63;
  const int l15 = lane & 15, quad = lane >> 4;
  const int m0 = blockIdx.x * (64 * MI) + wave * (16 * MI);
  const int n0 = blockIdx.y * 64;

  const float* xbase = X + (size_t)(m0 + l15) * DM + quad * 8;
  const short* wtbase = WT + (size_t)(n0 + l15) * DM + quad * 8;

  const f32x4 z = {0.f, 0.f, 0.f, 0.f};
  f32x4 acc[MI][4];
#pragma unroll
  for (int i = 0; i < MI; ++i)
#pragma unroll
    for (int j = 0; j < 4; ++j) acc[i][j] = z;

  bf16x8 a_cur[MI], b_cur[4];
#pragma unroll
  for (int i = 0; i < MI; ++i) a_cur[i] = cvt8(xbase + i * 16 * DM);
#pragma unroll
  for (int j = 0; j < 4; ++j) b_cur[j] = *(const bf16x8*)(wtbase + j * 16 * DM);

#pragma unroll 2
  for (int ks = 0; ks < DM / 32; ++ks) {
    bf16x8 a_nxt[MI], b_nxt[4];
    if (ks < DM / 32 - 1) {
      const float* xp = xbase + (ks + 1) * 32;
      const short* wp = wtbase + (ks + 1) * 32;
#pragma unroll
      for (int i = 0; i < MI; ++i) a_nxt[i] = cvt8(xp + i * 16 * DM);
#pragma unroll
      for (int j = 0; j < 4; ++j) b_nxt[j] = *(const bf16x8*)(wp + j * 16 * DM);
    } else {
#pragma unroll
      for (int i = 0; i < MI; ++i) a_nxt[i] = a_cur[i];
#pragma unroll
      for (int j = 0; j < 4; ++j) b_nxt[j] = b_cur[j];
    }
#pragma unroll
    for (int i = 0; i < MI; ++i)
#pragma unroll
      for (int j = 0; j < 4; ++j)
        acc[i][j] = __builtin_amdgcn_mfma_f32_16x16x32_bf16(a_cur[i], b_cur[j],
                                                            acc[i][j], 0, 0, 0);
#pragma unroll
    for (int i = 0; i < MI; ++i) a_cur[i] = a_nxt[i];
#pragma unroll
    for (int j = 0; j < 4; ++j) b_cur[j] = b_nxt[j];
  }

  // C/D layout: col = lane&15, row = quad*4 + reg  [verified m89]
#pragma unroll
  for (int i = 0; i < MI; ++i)
#pragma unroll
    for (int j = 0; j < 4; ++j)
#pragma unroll
      for (int r = 0; r < 4; ++r)
        O[(size_t)(m0 + i * 16 + quad * 4 + r) * Ncols + n0 + j * 16 + l15] =
            f2bf(acc[i][j][r]);
}

// w_I[row][4] = x_q[row] @ Ww  (f32 exact). One block per row, coalesced reads.
__global__ __launch_bounds__(256) void wproj_kernel(const float* __restrict__ X,
                                                    const float* __restrict__ Ww,
                                                    float* __restrict__ wI) {
  const int row = blockIdx.x;
  const int tid = threadIdx.x;
  f32x4 acc = {0.f, 0.f, 0.f, 0.f};
  const float* xr = X + (size_t)row * DM;
  for (int t = tid; t < DM; t += 256) {
    float xv = xr[t];
    f32x4 w4 = *(const f32x4*)&Ww[t * 4];   // Ww is [2048][4] row-major
    acc += w4 * xv;
  }
  __shared__ f32x4 red[256];
  red[tid] = acc;
  __syncthreads();
  for (int s = 128; s > 0; s >>= 1) {
    if (tid < s) red[tid] += red[tid + s];
    __syncthreads();
  }
  if (tid == 0) *(f32x4*)&wI[(size_t)row * 4] = red[0];
}

// out[b][q][k] = sum_h wI[b,q,h] * relu( sum_d qb[b,q,h,d]*kb[b,k,d] )
// Block: 256 thr (4 waves), 128x128 output tile; wave = 64x64; no LDS, no barriers.
__global__ __launch_bounds__(256, 2) void score_kernel(const short* __restrict__ qb,
                                                       const short* __restrict__ kb,
                                                       const float* __restrict__ wI,
                                                       float* __restrict__ out) {
  const int b = blockIdx.z;
  const int qt = blockIdx.y;
  const int kt = blockIdx.x;
  const int tid = threadIdx.x;
  const int wave = tid >> 6, lane = tid & 63;
  const int wm = wave >> 1, wn = wave & 1;
  const int l15 = lane & 15, quad = lane >> 4;

  // Key fragments: loaded once, reused across all 4 heads.
  // B-frag layout: B[k=quad*8+j][n=lane&15] -> read kb[key=n][d] 16B contiguous.
  bf16x8 bf[4][2];
  {
    const short* kbase =
        kb + (size_t)(b * TKS + kt * 128 + wn * 64 + l15) * DI + quad * 8;
#pragma unroll
    for (int j = 0; j < 4; ++j)
#pragma unroll
      for (int ks = 0; ks < 2; ++ks)
        bf[j][ks] = *(const bf16x8*)(kbase + j * 16 * DI + ks * 32);
  }

  const f32x4 z = {0.f, 0.f, 0.f, 0.f};
  f32x4 facc[4][4];
#pragma unroll
  for (int i = 0; i < 4; ++i)
#pragma unroll
    for (int j = 0; j < 4; ++j) facc[i][j] = z;

  const short* qbase =
      qb + (size_t)(b * TQS + qt * 128 + wm * 64 + l15) * (NH * DI) + quad * 8;
  const float* wbase = wI + (size_t)(b * TQS + qt * 128 + wm * 64 + quad * 4) * NH;

#pragma unroll 1
  for (int h = 0; h < NH; ++h) {
    // A-frag layout: A[m=lane&15][k=quad*8+j] -> read qb[row=m][h*64 + d] 16B contiguous.
    bf16x8 af[4][2];
#pragma unroll
    for (int i = 0; i < 4; ++i)
#pragma unroll
      for (int ks = 0; ks < 2; ++ks)
        af[i][ks] = *(const bf16x8*)(qbase + h * DI + i * 16 * (NH * DI) + ks * 32);

    f32x4 acc[4][4];
#pragma unroll
    for (int i = 0; i < 4; ++i)
#pragma unroll
      for (int j = 0; j < 4; ++j) acc[i][j] = z;

#pragma unroll
    for (int ks = 0; ks < 2; ++ks)
#pragma unroll
      for (int i = 0; i < 4; ++i)
#pragma unroll
        for (int j = 0; j < 4; ++j)
          acc[i][j] = __builtin_amdgcn_mfma_f32_16x16x32_bf16(af[i][ks], bf[j][ks],
                                                              acc[i][j], 0, 0, 0);

    // relu * w, accumulate over heads. C row = quad*4+r (q index), col = l15 (k index).
#pragma unroll
    for (int i = 0; i < 4; ++i) {
      float wv[4];
#pragma unroll
      for (int r = 0; r < 4; ++r) wv[r] = wbase[(i * 16 + r) * NH + h];
#pragma unroll
      for (int j = 0; j < 4; ++j)
#pragma unroll
        for (int r = 0; r < 4; ++r)
          facc[i][j][r] += wv[r] * fmaxf(acc[i][j][r], 0.f);
    }
  }

  float* obase = out + (size_t)b * TQS * TKS +
                 (size_t)(qt * 128 + wm * 64 + quad * 4) * TKS + kt * 128 + wn * 64 + l15;
#pragma unroll
  for (int i = 0; i < 4; ++i)
#pragma unroll
    for (int r = 0; r < 4; ++r)
#pragma unroll
      for (int j = 0; j < 4; ++j)
        obase[(size_t)(i * 16 + r) * TKS + j * 16] = facc[i][j][r];
}

extern "C" void kernel_launch(void* const* d_in, const int* in_sizes, int n_in,
                              void* d_out, int out_size, void* d_ws, size_t ws_size,
                              hipStream_t stream) {
  const float* x_q = (const float*)d_in[0];  // [2,4096,2048]
  const float* x_k = (const float*)d_in[1];  // [2,4096,2048]
  const float* Wq  = (const float*)d_in[2];  // [2048,256]
  const float* Ww  = (const float*)d_in[3];  // [2048,4]
  const float* Wk  = (const float*)d_in[4];  // [2048,64]
  float* out = (float*)d_out;                // [2,4096,4096]

  char* ws = (char*)d_ws;
  short* qbuf = (short*)(ws);                              // 8192*256 bf16 = 4 MB
  short* kbuf = (short*)(ws + (4u << 20));                 // 8192*64  bf16 = 1 MB
  float* wIb  = (float*)(ws + (5u << 20));                 // 8192*4 f32 = 128 KB
  short* WqT  = (short*)(ws + (5u << 20) + (128u << 10));  // 256*2048 bf16 = 1 MB
  short* WkT  = (short*)(ws + (6u << 20) + (128u << 10));  // 64*2048 bf16 = 256 KB

  // Weights -> transposed bf16 (so MFMA B-fragments are contiguous 16B loads)
  transpose_cast_kernel<<<(256 * 2048) / 256, 256, 0, stream>>>(Wq, WqT, 256);
  transpose_cast_kernel<<<(64 * 2048) / 256, 256, 0, stream>>>(Wk, WkT, 64);

  // Projections (bf16 MFMA GEMMs)
  proj_kernel<2><<<dim3((BB * TQS) / 128, 256 / 64), 256, 0, stream>>>(x_q, WqT, qbuf, 256);
  proj_kernel<1><<<dim3((BB * TKS) / 64, 64 / 64), 256, 0, stream>>>(x_k, WkT, kbuf, 64);

  // w_I in f32
  wproj_kernel<<<BB * TQS, 256, 0, stream>>>(x_q, Ww, wIb);

  // Fused per-head QK^T -> relu -> weighted head sum
  score_kernel<<<dim3(TKS / 128, TQS / 128, BB), 256, 0, stream>>>(qbuf, kbuf, wIb, out);
}

// Round 2
// 343.523 us; speedup vs baseline: 1.0896x; 1.0896x over previous
//
#include <hip/hip_runtime.h>
#include <hip/hip_bf16.h>

#define DM 2048
#define NH 4
#define DI 64
#define TQS 4096
#define TKS 4096
#define BB 2

typedef __attribute__((ext_vector_type(4))) float f32x4;
typedef __attribute__((ext_vector_type(8))) short bf16x8;

__device__ __forceinline__ short f2bf(float f) {
  __hip_bfloat16 h = __float2bfloat16(f);
  return __builtin_bit_cast(short, h);
}

__device__ __forceinline__ bf16x8 cvt8(f32x4 a, f32x4 b) {
  bf16x8 r;
  r[0] = f2bf(a[0]); r[1] = f2bf(a[1]); r[2] = f2bf(a[2]); r[3] = f2bf(a[3]);
  r[4] = f2bf(b[0]); r[5] = f2bf(b[1]); r[6] = f2bf(b[2]); r[7] = f2bf(b[3]);
  return r;
}

// WqwT[320][2048]: rows 0-255 = Wq cols, 256-259 = Ww cols, 260-319 = 0.
__global__ __launch_bounds__(256) void transpose_qw(const float* __restrict__ Wq,
                                                    const float* __restrict__ Ww,
                                                    short* __restrict__ WT) {
  int idx = blockIdx.x * 256 + threadIdx.x;  // n*2048 + k
  int n = idx >> 11, k = idx & 2047;
  float v = 0.f;
  if (n < 256) v = Wq[(size_t)k * 256 + n];
  else if (n < 260) v = Ww[(size_t)k * 4 + (n - 256)];
  WT[idx] = f2bf(v);
}

// WkT[64][2048]
__global__ __launch_bounds__(256) void transpose_k(const float* __restrict__ Wk,
                                                   short* __restrict__ WT) {
  int idx = blockIdx.x * 256 + threadIdx.x;
  int n = idx >> 11, k = idx & 2047;
  WT[idx] = f2bf(Wk[(size_t)k * 64 + n]);
}

// One block = 64 rows x (NJ*4 waves' worth of) columns. Waves split COLUMNS:
// wave w owns column-tiles {w, 4+w, 8+w, 12+w} (+ {16+w} for q-path); all waves
// read the same 64 A rows (L1-shared). A pipelined depth-2, B depth-1.
template <int NJ, bool QP>
__device__ __forceinline__ void proj_body(const float* __restrict__ X,
                                          const short* __restrict__ WT,
                                          short* __restrict__ O,
                                          float* __restrict__ wI, int blk) {
  const int tid = threadIdx.x;
  const int wave = tid >> 6, lane = tid & 63;
  const int l15 = lane & 15, quad = lane >> 4;
  const int m0 = blk * 64;
  const int ldo = QP ? 256 : 64;

  int jt[NJ];
#pragma unroll
  for (int jj = 0; jj < NJ; ++jj) jt[jj] = QP ? (jj < 4 ? jj * 4 + wave : 16 + wave) : wave;

  const float* xbase = X + (size_t)(m0 + l15) * DM + quad * 8;
  const short* wb[NJ];
#pragma unroll
  for (int jj = 0; jj < NJ; ++jj) wb[jj] = WT + (size_t)(jt[jj] * 16 + l15) * DM + quad * 8;

  const f32x4 z = {0.f, 0.f, 0.f, 0.f};
  f32x4 acc[NJ][4];
#pragma unroll
  for (int jj = 0; jj < NJ; ++jj)
#pragma unroll
    for (int i = 0; i < 4; ++i) acc[jj][i] = z;

  // A pipeline: two stages in flight (raw f32)
  f32x4 araw[2][4][2];
#pragma unroll
  for (int i = 0; i < 4; ++i) {
    araw[0][i][0] = *(const f32x4*)(xbase + i * 16 * DM);
    araw[0][i][1] = *(const f32x4*)(xbase + i * 16 * DM + 4);
    araw[1][i][0] = *(const f32x4*)(xbase + i * 16 * DM + 32);
    araw[1][i][1] = *(const f32x4*)(xbase + i * 16 * DM + 36);
  }
  bf16x8 bcur[NJ];
#pragma unroll
  for (int jj = 0; jj < NJ; ++jj) bcur[jj] = *(const bf16x8*)wb[jj];

#pragma unroll 2
  for (int ks = 0; ks < 64; ++ks) {
    const int s = ks & 1;
    bf16x8 abf[4];
#pragma unroll
    for (int i = 0; i < 4; ++i) abf[i] = cvt8(araw[s][i][0], araw[s][i][1]);
    if (ks < 62) {  // refill consumed stage for iter ks+2
      const float* xp = xbase + (ks + 2) * 32;
#pragma unroll
      for (int i = 0; i < 4; ++i) {
        araw[s][i][0] = *(const f32x4*)(xp + i * 16 * DM);
        araw[s][i][1] = *(const f32x4*)(xp + i * 16 * DM + 4);
      }
    }
    bf16x8 bnxt[NJ];
    if (ks < 63) {
#pragma unroll
      for (int jj = 0; jj < NJ; ++jj) bnxt[jj] = *(const bf16x8*)(wb[jj] + (ks + 1) * 32);
    } else {
#pragma unroll
      for (int jj = 0; jj < NJ; ++jj) bnxt[jj] = bcur[jj];
    }
#pragma unroll
    for (int jj = 0; jj < NJ; ++jj)
#pragma unroll
      for (int i = 0; i < 4; ++i)
        acc[jj][i] = __builtin_amdgcn_mfma_f32_16x16x32_bf16(abf[i], bcur[jj],
                                                             acc[jj][i], 0, 0, 0);
#pragma unroll
    for (int jj = 0; jj < NJ; ++jj) bcur[jj] = bnxt[jj];
  }

  // C/D: row = quad*4 + r, col = l15
#pragma unroll
  for (int jj = 0; jj < NJ; ++jj) {
    if (QP && jt[jj] >= 16) {
      if (jt[jj] == 16 && l15 < 4) {  // Ww columns -> wI (f32)
#pragma unroll
        for (int i = 0; i < 4; ++i)
#pragma unroll
          for (int r = 0; r < 4; ++r)
            wI[(size_t)(m0 + i * 16 + quad * 4 + r) * NH + l15] = acc[jj][i][r];
      }
    } else {
#pragma unroll
      for (int i = 0; i < 4; ++i)
#pragma unroll
        for (int r = 0; r < 4; ++r)
          O[(size_t)(m0 + i * 16 + quad * 4 + r) * ldo + jt[jj] * 16 + l15] =
              f2bf(acc[jj][i][r]);
    }
  }
}

__global__ __launch_bounds__(256, 1) void proj_fused(const float* __restrict__ xq,
                                                     const float* __restrict__ xk,
                                                     const short* __restrict__ WqwT,
                                                     const short* __restrict__ WkT,
                                                     short* __restrict__ qb,
                                                     short* __restrict__ kb,
                                                     float* __restrict__ wIb) {
  if (blockIdx.x < 128)
    proj_body<5, true>(xq, WqwT, qb, wIb, blockIdx.x);
  else
    proj_body<1, false>(xk, WkT, kb, nullptr, blockIdx.x - 128);
}

// out[b][q][k] = sum_h wI[b,q,h] * relu(qb[b,q,h,:] . kb[b,k,:])
// 128x128 tile/block, 4 waves of 64x64. No LDS/barriers; af double-buffered over heads.
__global__ __launch_bounds__(256, 2) void score_kernel(const short* __restrict__ qb,
                                                       const short* __restrict__ kb,
                                                       const float* __restrict__ wI,
                                                       float* __restrict__ out) {
  const int b = blockIdx.z;
  const int qt = blockIdx.y;
  const int kt = blockIdx.x;
  const int tid = threadIdx.x;
  const int wave = tid >> 6, lane = tid & 63;
  const int wm = wave >> 1, wn = wave & 1;
  const int l15 = lane & 15, quad = lane >> 4;

  // Key fragments: B[k=quad*8+j][n=l15]; reused across all heads.
  bf16x8 bf[4][2];
  {
    const short* kbase =
        kb + (size_t)(b * TKS + kt * 128 + wn * 64 + l15) * DI + quad * 8;
#pragma unroll
    for (int j = 0; j < 4; ++j)
#pragma unroll
      for (int ks = 0; ks < 2; ++ks)
        bf[j][ks] = *(const bf16x8*)(kbase + j * 16 * DI + ks * 32);
  }

  const f32x4 z = {0.f, 0.f, 0.f, 0.f};
  f32x4 facc[4][4];
#pragma unroll
  for (int i = 0; i < 4; ++i)
#pragma unroll
    for (int j = 0; j < 4; ++j) facc[i][j] = z;

  const short* qbase =
      qb + (size_t)(b * TQS + qt * 128 + wm * 64 + l15) * (NH * DI) + quad * 8;
  const float* wbase = wI + (size_t)(b * TQS + qt * 128 + wm * 64 + quad * 4) * NH;

  bf16x8 af[2][4][2];
#pragma unroll
  for (int i = 0; i < 4; ++i)
#pragma unroll
    for (int ks = 0; ks < 2; ++ks)
      af[0][i][ks] = *(const bf16x8*)(qbase + i * 16 * (NH * DI) + ks * 32);

#pragma unroll
  for (int h = 0; h < NH; ++h) {
    if (h < NH - 1) {  // prefetch next head's A fragments (covered by MFMA+epilogue)
#pragma unroll
      for (int i = 0; i < 4; ++i)
#pragma unroll
        for (int ks = 0; ks < 2; ++ks)
          af[(h + 1) & 1][i][ks] =
              *(const bf16x8*)(qbase + (h + 1) * DI + i * 16 * (NH * DI) + ks * 32);
    }

    f32x4 acc[4][4];
#pragma unroll
    for (int i = 0; i < 4; ++i)
#pragma unroll
      for (int j = 0; j < 4; ++j) acc[i][j] = z;

#pragma unroll
    for (int ks = 0; ks < 2; ++ks)
#pragma unroll
      for (int i = 0; i < 4; ++i)
#pragma unroll
        for (int j = 0; j < 4; ++j)
          acc[i][j] = __builtin_amdgcn_mfma_f32_16x16x32_bf16(
              af[h & 1][i][ks], bf[j][ks], acc[i][j], 0, 0, 0);

#pragma unroll
    for (int i = 0; i < 4; ++i) {
      float wv[4];
#pragma unroll
      for (int r = 0; r < 4; ++r) wv[r] = wbase[(i * 16 + r) * NH + h];
#pragma unroll
      for (int j = 0; j < 4; ++j)
#pragma unroll
        for (int r = 0; r < 4; ++r)
          facc[i][j][r] += wv[r] * fmaxf(acc[i][j][r], 0.f);
    }
  }

  float* obase = out + (size_t)b * TQS * TKS +
                 (size_t)(qt * 128 + wm * 64 + quad * 4) * TKS + kt * 128 + wn * 64 + l15;
#pragma unroll
  for (int i = 0; i < 4; ++i)
#pragma unroll
    for (int r = 0; r < 4; ++r)
#pragma unroll
      for (int j = 0; j < 4; ++j)
        __builtin_nontemporal_store(facc[i][j][r],
                                    &obase[(size_t)(i * 16 + r) * TKS + j * 16]);
}

extern "C" void kernel_launch(void* const* d_in, const int* in_sizes, int n_in,
                              void* d_out, int out_size, void* d_ws, size_t ws_size,
                              hipStream_t stream) {
  const float* x_q = (const float*)d_in[0];  // [2,4096,2048]
  const float* x_k = (const float*)d_in[1];  // [2,4096,2048]
  const float* Wq  = (const float*)d_in[2];  // [2048,256]
  const float* Ww  = (const float*)d_in[3];  // [2048,4]
  const float* Wk  = (const float*)d_in[4];  // [2048,64]
  float* out = (float*)d_out;                // [2,4096,4096]

  char* ws = (char*)d_ws;
  short* qbuf = (short*)(ws);                              // 8192*256 bf16 = 4 MB
  short* kbuf = (short*)(ws + (4u << 20));                 // 8192*64  bf16 = 1 MB
  float* wIb  = (float*)(ws + (5u << 20));                 // 8192*4 f32 = 128 KB
  short* WqwT = (short*)(ws + (5u << 20) + (128u << 10));  // 320*2048 bf16 = 1.25 MB
  short* WkT  = (short*)(ws + (7u << 20));                 // 64*2048 bf16 = 256 KB

  transpose_qw<<<(320 * 2048) / 256, 256, 0, stream>>>(Wq, Ww, WqwT);
  transpose_k<<<(64 * 2048) / 256, 256, 0, stream>>>(Wk, WkT);

  // Fused projections: blocks 0-127 -> q (+w), 128-255 -> k. x read exactly once.
  proj_fused<<<256, 256, 0, stream>>>(x_q, x_k, WqwT, WkT, qbuf, kbuf, wIb);

  score_kernel<<<dim3(TKS / 128, TQS / 128, BB), 256, 0, stream>>>(qbuf, kbuf, wIb, out);
}